// Round 9
// baseline (146.132 us; speedup 1.0000x reference)
//
#include <hip/hip_runtime.h>

// Problem constants (from setup_inputs)
#define B_     2
#define NQ     16384     // B*N
#define M2     8192
#define M3     4096
#define M4     2048
#define NBIN   64
#define GDOT_BLOCKS 7168
#define SCAT_K_BLOCKS 112   // 32+32+16+16+8+8
#define SCAT_Q_BLOCKS 64    // 32+32
#define K2_BLOCKS (GDOT_BLOCKS + SCAT_K_BLOCKS + SCAT_Q_BLOCKS)
#define NCH    8            // window chunks per (qtile, level)
#define NWID   (256*3*NCH)  // 6144 scan waves

// Referee model (jax/XLA, verified R4): d = (su - 2*p) + sk, left-to-right fp32.
// su/sk: elementwise square + sequential reduce, NO FMA.
// p: K=3 GEMM ascending-k FMA chain. fl(2p) exact -> fmaf(-2,p,su) form ok.
__device__ __forceinline__ float np_sqnorm(float x, float y, float z) {
    return __fadd_rn(__fadd_rn(__fmul_rn(x, x), __fmul_rn(y, y)), __fmul_rn(z, z));
}
__device__ __forceinline__ float ref_dist(float su, float ux, float uy, float uz,
                                          float kx, float ky, float kz, float sk) {
    float p = fmaf(uz, kz, fmaf(uy, ky, __fmul_rn(ux, kx)));
    return __fadd_rn(fmaf(-2.0f, p, su), sk);
}
__device__ __forceinline__ int zbin(float z) {
    int b = (int)(z * 64.0f);
    return min(63, max(0, b));
}
__device__ __forceinline__ int wave_min_i(int v) {
    for (int o = 32; o; o >>= 1) v = min(v, __shfl_xor(v, o, 64));
    return v;
}
__device__ __forceinline__ int wave_max_i(int v) {
    for (int o = 32; o; o >>= 1) v = max(v, __shfl_xor(v, o, 64));
    return v;
}

// ---------------------------------------------------------------- kernel 1
// wc fold (blocks 0-1) + per-group z-hist + prefix (blocks 2-9).
// Groups: 0,1=lvl2 b0,b1  2,3=lvl3  4,5=lvl4  6,7=queries b0,b1.
__global__ void k_setup_v9(const float* __restrict__ w_fc, const float* __restrict__ w_cls,
                           const float* __restrict__ pts,
                           const float* __restrict__ xyz2, const float* __restrict__ xyz3,
                           const float* __restrict__ xyz4,
                           float* __restrict__ wc, int* __restrict__ bs,
                           int* __restrict__ cur) {
    int bx = blockIdx.x, tid = threadIdx.x;
    if (bx < 2) {
        int c = bx * 256 + tid;
        if (c < 320) {
            float acc = 0.f;
#pragma unroll
            for (int j = 0; j < 64; ++j) acc = fmaf(w_fc[c * 64 + j], w_cls[j], acc);
            wc[c] = acc;
        }
        return;
    }
    int g = bx - 2;
    const float* src; int M;
    if (g < 2)      { src = xyz2 + g * M2 * 3;       M = M2; }
    else if (g < 4) { src = xyz3 + (g - 2) * M3 * 3; M = M3; }
    else if (g < 6) { src = xyz4 + (g - 4) * M4 * 3; M = M4; }
    else            { src = pts  + (g - 6) * 8192 * 3; M = 8192; }
    __shared__ int h[NBIN];
    if (tid < NBIN) h[tid] = 0;
    __syncthreads();
    for (int j = tid; j < M; j += 256) atomicAdd(&h[zbin(src[j * 3 + 2])], 1);
    __syncthreads();
    if (tid == 0) {
        int run = 0;
        for (int b = 0; b < NBIN; ++b) { bs[g * 65 + b] = run; run += h[b]; }
        bs[g * 65 + 64] = run;
    }
    __syncthreads();
    if (tid < NBIN) cur[g * 64 + tid] = bs[g * 65 + tid];
}

// ---------------------------------------------------------------- kernel 2
// gdot (one wave per known point) + z-binned scatter of known pts & queries.
__global__ void k_build_v9(const float* __restrict__ pts,
                           const float* __restrict__ xyz2, const float* __restrict__ xyz3,
                           const float* __restrict__ xyz4,
                           const float* __restrict__ f2, const float* __restrict__ f3,
                           const float* __restrict__ f4, const float* __restrict__ wc,
                           float* __restrict__ g2, float* __restrict__ g3,
                           float* __restrict__ g4,
                           float4* __restrict__ pk, int* __restrict__ oi,
                           float4* __restrict__ uq, int* __restrict__ qmap,
                           int* __restrict__ cur) {
    int bx = blockIdx.x, tid = threadIdx.x;
    if (bx < GDOT_BLOCKS) {
        int gid  = bx * 256 + tid;
        int w    = gid >> 6;
        int lane = gid & 63;
        float v;
        if (w < 16384) {
            v = f2[(size_t)w * 64 + lane] * wc[lane];
        } else if (w < 24576) {
            size_t base = (size_t)(w - 16384) * 128;
            v = fmaf(f3[base + 64 + lane], wc[128 + lane], f3[base + lane] * wc[64 + lane]);
        } else {
            size_t base = (size_t)(w - 24576) * 128;
            v = fmaf(f4[base + 64 + lane], wc[256 + lane], f4[base + lane] * wc[192 + lane]);
        }
        for (int off = 32; off; off >>= 1) v += __shfl_down(v, off, 64);
        if (lane == 0) {
            if (w < 16384) g2[w] = v;
            else if (w < 24576) g3[w - 16384] = v;
            else g4[w - 24576] = v;
        }
        return;
    }
    bx -= GDOT_BLOCKS;
    __shared__ int cnt[NBIN], base[NBIN];
    if (tid < NBIN) cnt[tid] = 0;
    __syncthreads();
    if (bx < SCAT_K_BLOCKS) {
        int g, j0;
        if (bx < 32)       { g = 0; j0 = bx * 256; }
        else if (bx < 64)  { g = 1; j0 = (bx - 32) * 256; }
        else if (bx < 80)  { g = 2; j0 = (bx - 64) * 256; }
        else if (bx < 96)  { g = 3; j0 = (bx - 80) * 256; }
        else if (bx < 104) { g = 4; j0 = (bx - 96) * 256; }
        else               { g = 5; j0 = (bx - 104) * 256; }
        const float* src = (g < 2) ? xyz2 + g * M2 * 3
                         : (g < 4) ? xyz3 + (g - 2) * M3 * 3
                                   : xyz4 + (g - 4) * M4 * 3;
        int gb = (g < 2) ? g * M2 : (g < 4) ? 16384 + (g - 2) * M3 : 24576 + (g - 4) * M4;
        int j = j0 + tid;
        float x = src[j * 3], y = src[j * 3 + 1], z = src[j * 3 + 2];
        int bin = zbin(z);
        int off = atomicAdd(&cnt[bin], 1);
        __syncthreads();
        if (tid < NBIN) base[tid] = atomicAdd(&cur[g * 64 + tid], cnt[tid]);
        __syncthreads();
        int slot = gb + base[bin] + off;
        pk[slot] = make_float4(x, y, z, np_sqnorm(x, y, z));
        oi[slot] = j;                          // orig index within (level,batch)
        return;
    }
    bx -= SCAT_K_BLOCKS;
    {   // query scatter
        int b = bx >> 5;
        int j = (bx & 31) * 256 + tid;         // [0,8192) within batch
        const float* src = pts + (size_t)b * 8192 * 3;
        float x = src[j * 3], y = src[j * 3 + 1], z = src[j * 3 + 2];
        int bin = zbin(z);
        int g = 6 + b;
        int off = atomicAdd(&cnt[bin], 1);
        __syncthreads();
        if (tid < NBIN) base[tid] = atomicAdd(&cur[g * 64 + tid], cnt[tid]);
        __syncthreads();
        int slot = b * 8192 + base[bin] + off;
        uq[slot]   = make_float4(x, y, z, np_sqnorm(x, y, z));
        qmap[slot] = b * 8192 + j;             // orig global query index
    }
}

// ---------------------------------------------------------------- kernel 3
// T-pass: 768 independent waves, one per (qtile, level). Each lane scans the
// wave's own-bin range values-only -> per-query certified T (3rd-min over a
// subset >= referee d3). No barriers.
#define STEP_A(KV)                                                          \
    {                                                                       \
        float d_ = ref_dist(suq, ux, uy, uz, KV.x, KV.y, KV.z, KV.w);       \
        float m1_ = __builtin_amdgcn_fmed3f(d_, a0, a1);                    \
        float m2_ = __builtin_amdgcn_fmed3f(d_, a1, a2);                    \
        a0 = fminf(d_, a0); a1 = m1_; a2 = m2_;                             \
    }

__launch_bounds__(256)
__global__ void k_tpass_v9(const float4* __restrict__ pk, const float4* __restrict__ uq,
                           const int* __restrict__ bs, float* __restrict__ Tarr) {
    int wid  = blockIdx.x * 4 + (threadIdx.x >> 6);   // 0..767
    int lane = threadIdx.x & 63;
    int qtile = wid / 3;
    int lvl   = wid - qtile * 3;
    int b     = qtile >> 7;
    int sq    = (qtile << 6) + lane;

    float4 u = uq[sq];
    float ux = u.x, uy = u.y, uz = u.z, suq = u.w;

    int gb = (lvl == 0) ? b * M2 : (lvl == 1) ? 16384 + b * M3 : 24576 + b * M4;
    const float4* pkg = pk + gb;
    const int*    bsg = bs + (lvl * 2 + b) * 65;

    int bq  = zbin(uz);
    int blo = __builtin_amdgcn_readfirstlane(wave_min_i(bq));
    int bhi = __builtin_amdgcn_readfirstlane(wave_max_i(bq));
    int S0  = bsg[blo], E0 = bsg[bhi + 1];

    float a0 = 3e38f, a1 = 3e38f, a2 = 3e38f;
    int t = S0;
    for (; t + 4 <= E0; t += 4) {
        float4 k0 = pkg[t], k1 = pkg[t + 1], k2 = pkg[t + 2], k3 = pkg[t + 3];
        STEP_A(k0); STEP_A(k1); STEP_A(k2); STEP_A(k3);
    }
    for (; t < E0; ++t) { float4 kv = pkg[t]; STEP_A(kv); }
    Tarr[lvl * NQ + sq] = a2;
}

// ---------------------------------------------------------------- kernel 4
// Windowed scan: 6144 independent waves = (qtile, level, chunk/8). Slots init
// to Tp = nextafter(T); gated lex-(d, orig_idx) insert (deterministic under
// nondeterministic bin scatter; reproduces stable top-k ties). Window = bins
// covering z +- sqrt(T+1e-5); margin 1e-5 >> 4e-6 fp32 rounding -> exact.
#define LEX_INS(D, O)                                                       \
    {                                                                       \
        bool l2_ = ((D) < e2) || ((D) == e2 && (O) < j2v);                  \
        bool l1_ = ((D) < e1) || ((D) == e1 && (O) < j1v);                  \
        bool l0_ = ((D) < e0) || ((D) == e0 && (O) < j0v);                  \
        j2v = l1_ ? j1v : (l2_ ? (O) : j2v);  e2 = l1_ ? e1 : (l2_ ? (D) : e2); \
        j1v = l0_ ? j0v : (l1_ ? (O) : j1v);  e1 = l0_ ? e0 : (l1_ ? (D) : e1); \
        j0v = l0_ ? (O) : j0v;                e0 = l0_ ? (D) : e0;          \
    }

#define STEP_B(KV, O)                                                       \
    {                                                                       \
        float db_ = ref_dist(suq, ux, uy, uz, KV.x, KV.y, KV.z, KV.w);      \
        if (__any(db_ <= e2)) { int ob_ = (O); LEX_INS(db_, ob_); }         \
    }

__launch_bounds__(256)
__global__ void k_scanW_v9(const float4* __restrict__ pk, const int* __restrict__ oi,
                           const float4* __restrict__ uq, const int* __restrict__ bs,
                           const float* __restrict__ Tarr,
                           float* __restrict__ nd, int* __restrict__ ni) {
    int wid  = blockIdx.x * 4 + (threadIdx.x >> 6);   // 0..6143
    int lane = threadIdx.x & 63;
    int qtile = wid / 24;
    int r     = wid - qtile * 24;
    int lvl   = r >> 3;
    int chunk = r & 7;
    int b     = qtile >> 7;
    int sq    = (qtile << 6) + lane;

    float4 u = uq[sq];
    float ux = u.x, uy = u.y, uz = u.z, suq = u.w;
    float T  = Tarr[lvl * NQ + sq];

    // per-lane window bins; union over wave
    float s = sqrtf(__fadd_rn(T, 1e-5f));
    float fbl = fmaxf(0.f, fminf(63.f, (uz - s) * 64.f));
    float fbh = fmaxf(0.f, fminf(63.f, (uz + s) * 64.f));
    int bl = (int)fbl, bh = (int)fbh;
    int BL = __builtin_amdgcn_readfirstlane(wave_min_i(bl));
    int BH = __builtin_amdgcn_readfirstlane(wave_max_i(bh));

    int gb = (lvl == 0) ? b * M2 : (lvl == 1) ? 16384 + b * M3 : 24576 + b * M4;
    const float4* pkg = pk + gb;
    const int*    oig = oi + gb;
    const int*    bsg = bs + (lvl * 2 + b) * 65;

    int S = bsg[BL], E = bsg[BH + 1];
    int L = E - S;
    int wa = __builtin_amdgcn_readfirstlane(S + ((L * chunk) >> 3));
    int we = __builtin_amdgcn_readfirstlane(S + ((L * (chunk + 1)) >> 3));

    // Tp = next float above T (d == T must remain insertable)
    int tb = __float_as_int(T);
    float Tp = (T > 0.f) ? __int_as_float(tb + 1)
             : (T < 0.f) ? __int_as_float(tb - 1) : 1e-45f;
    float e0 = Tp, e1 = Tp, e2 = Tp;
    int j0v = 0x7fffffff, j1v = 0x7fffffff, j2v = 0x7fffffff;

    int t = wa;
    for (; t + 4 <= we; t += 4) {
        float4 k0 = pkg[t], k1 = pkg[t + 1], k2 = pkg[t + 2], k3 = pkg[t + 3];
        int o0 = oig[t], o1 = oig[t + 1], o2 = oig[t + 2], o3 = oig[t + 3];
        STEP_B(k0, o0); STEP_B(k1, o1); STEP_B(k2, o2); STEP_B(k3, o3);
    }
    for (; t < we; ++t) { float4 kv = pkg[t]; STEP_B(kv, oig[t]); }

    int base = wid * 192 + lane;
    nd[base]       = e0;  ni[base]       = j0v;
    nd[base + 64]  = e1;  ni[base + 64]  = j1v;
    nd[base + 128] = e2;  ni[base + 128] = j2v;
}

// ---------------------------------------------------------------- kernel 5
// Merge: one thread per sorted query; fold 8 chunk-triples per level with the
// same lex insert, bit-exact fp32 weights, f64 g-fold, scatter to out[qmap].
__global__ void k_merge_v9(const float* __restrict__ nd, const int* __restrict__ ni,
                           const int* __restrict__ qmap,
                           const float* __restrict__ g2, const float* __restrict__ g3,
                           const float* __restrict__ g4,
                           float* __restrict__ out) {
    int sq = blockIdx.x * 256 + threadIdx.x;
    if (sq >= NQ) return;
    int qtile = sq >> 6, lane = sq & 63;
    int b = sq >> 13;

    double acc = 0.0;
#pragma unroll
    for (int lvl = 0; lvl < 3; ++lvl) {
        float e0 = 3e38f, e1 = 3e38f, e2 = 3e38f;
        int j0v = 0x7fffffff, j1v = 0x7fffffff, j2v = 0x7fffffff;
#pragma unroll
        for (int c = 0; c < NCH; ++c) {
            int base = (qtile * 24 + lvl * 8 + c) * 192 + lane;
#pragma unroll
            for (int k = 0; k < 3; ++k) {
                float d = nd[base + k * 64];
                int   o = ni[base + k * 64];
                LEX_INS(d, o);
            }
        }
        const float* gl = (lvl == 0) ? g2 + b * M2
                        : (lvl == 1) ? g3 + b * M3 : g4 + b * M4;
        // referee weights, bit-exact fp32: r=1/(d+1e-8); w=r/((r0+r1)+r2)
        float r0 = __fdiv_rn(1.0f, __fadd_rn(e0, 1e-8f));
        float r1 = __fdiv_rn(1.0f, __fadd_rn(e1, 1e-8f));
        float r2 = __fdiv_rn(1.0f, __fadd_rn(e2, 1e-8f));
        float sw = __fadd_rn(__fadd_rn(r0, r1), r2);
        float w0 = __fdiv_rn(r0, sw), w1 = __fdiv_rn(r1, sw), w2 = __fdiv_rn(r2, sw);
        acc += (double)w0 * (double)gl[j0v] + (double)w1 * (double)gl[j1v]
             + (double)w2 * (double)gl[j2v];
    }
    out[qmap[sq]] = (float)acc;
}

// ---------------------------------------------------------------- launch
extern "C" void kernel_launch(void* const* d_in, const int* in_sizes, int n_in,
                              void* d_out, int out_size, void* d_ws, size_t ws_size,
                              hipStream_t stream) {
    const float* pts   = (const float*)d_in[0];
    const float* xyz2  = (const float*)d_in[1];
    const float* feat2 = (const float*)d_in[2];
    const float* xyz3  = (const float*)d_in[3];
    const float* feat3 = (const float*)d_in[4];
    const float* xyz4  = (const float*)d_in[5];
    const float* feat4 = (const float*)d_in[6];
    const float* w_fc  = (const float*)d_in[7];
    const float* w_cls = (const float*)d_in[8];
    float* out = (float*)d_out;

    // workspace layout (~10.7 MB)
    float4* pk   = (float4*)d_ws;            // 28672 float4
    float4* uq   = pk + 28672;               // 16384 float4
    float*  g2   = (float*)(uq + 16384);     // 16384
    float*  g3   = g2 + 16384;               // 8192
    float*  g4   = g3 + 8192;                // 4096
    float*  wc   = g4 + 4096;                // 320
    float*  Tarr = wc + 320;                 // 3*NQ = 49152
    int*    oi   = (int*)(Tarr + 49152);     // 28672
    int*    qmap = oi + 28672;               // 16384
    int*    bs   = qmap + 16384;             // 8*65
    int*    cur  = bs + 520;                 // 8*64
    float*  nd   = (float*)(cur + 512);      // NWID*192 = 1179648
    int*    ni   = (int*)(nd + (size_t)NWID * 192);

    k_setup_v9<<<10, 256, 0, stream>>>(w_fc, w_cls, pts, xyz2, xyz3, xyz4, wc, bs, cur);
    k_build_v9<<<K2_BLOCKS, 256, 0, stream>>>(pts, xyz2, xyz3, xyz4,
                                              feat2, feat3, feat4, wc,
                                              g2, g3, g4, pk, oi, uq, qmap, cur);
    k_tpass_v9<<<192, 256, 0, stream>>>(pk, uq, bs, Tarr);
    k_scanW_v9<<<NWID / 4, 256, 0, stream>>>(pk, oi, uq, bs, Tarr, nd, ni);
    k_merge_v9<<<64, 256, 0, stream>>>(nd, ni, qmap, g2, g3, g4, out);
}

// Round 10
// 128.686 us; speedup vs baseline: 1.1356x; 1.1356x over previous
//
#include <hip/hip_runtime.h>

// Problem constants (from setup_inputs)
#define B_     2
#define NQ     16384     // B*N
#define M2     8192
#define M3     4096
#define M4     2048
#define SEG    512       // known-points per segment job (pass B)
#define NLS    28        // 16 + 8 + 4 segment-jobs per query
#define NQT    256       // query tiles of 64 lanes
#define NJOBS  (NQT*NLS) // 7168 waves (pass B)
#define NLA    14        // pass-A jobs per qtile (8+4+2), 256 cands each
#define NJOBSA (NQT*NLA) // 3584 waves (pass A)

#define GDOT_BLOCKS 7168                        // 28672 waves, one per known point
#define PREP_THREADS (320 + NQ + B_*(M2+M3+M4)) // 45376
#define PREP_BLOCKS 178
#define FRONT_BLOCKS (GDOT_BLOCKS + PREP_BLOCKS)

// Referee model (jax/XLA, verified R4): d = (su - 2*p) + sk, left-to-right fp32.
// su/sk: elementwise square + sequential reduce, NO FMA.
// p: K=3 GEMM ascending-k FMA chain. fl(2p) exact -> fmaf(-2,p,su) form ok.
__device__ __forceinline__ float np_sqnorm(float x, float y, float z) {
    return __fadd_rn(__fadd_rn(__fmul_rn(x, x), __fmul_rn(y, y)), __fmul_rn(z, z));
}
__device__ __forceinline__ float ref_dist(float su, float ux, float uy, float uz,
                                          float kx, float ky, float kz, float sk) {
    float p = fmaf(uz, kz, fmaf(uy, ky, __fmul_rn(ux, kx)));
    return __fadd_rn(fmaf(-2.0f, p, su), sk);
}

// ---------------------------------------------------------------- kernel 1
// Fused front: gdot (blocks [0,7168)) + prep (blocks [7168,7346)).
__global__ void k_front_v10(const float* __restrict__ w_fc, const float* __restrict__ w_cls,
                            const float* __restrict__ pts,
                            const float* __restrict__ xyz2, const float* __restrict__ xyz3,
                            const float* __restrict__ xyz4,
                            const float* __restrict__ f2, const float* __restrict__ f3,
                            const float* __restrict__ f4,
                            float* __restrict__ wc, float* __restrict__ su,
                            float4* __restrict__ pk2, float4* __restrict__ pk3,
                            float4* __restrict__ pk4,
                            float* __restrict__ g2, float* __restrict__ g3,
                            float* __restrict__ g4) {
    if (blockIdx.x < GDOT_BLOCKS) {
        // g_lvl[b,m] = feat_lvl[b,m,:] . wc_slice  (one wave per known point)
        int gid  = blockIdx.x * 256 + threadIdx.x;
        int w    = gid >> 6;
        int lane = gid & 63;
        float v;
        if (w < 16384) {                         // level2: C=64, wc[0:64)
            v = f2[(size_t)w * 64 + lane] * wc[lane];
        } else if (w < 24576) {                  // level3: C=128, wc[64:192)
            size_t base = (size_t)(w - 16384) * 128;
            v = fmaf(f3[base + 64 + lane], wc[128 + lane], f3[base + lane] * wc[64 + lane]);
        } else {                                 // level4: C=128, wc[192:320)
            size_t base = (size_t)(w - 24576) * 128;
            v = fmaf(f4[base + 64 + lane], wc[256 + lane], f4[base + lane] * wc[192 + lane]);
        }
        for (int off = 32; off; off >>= 1) v += __shfl_down(v, off, 64);
        if (lane == 0) {
            if (w < 16384) g2[w] = v;
            else if (w < 24576) g3[w - 16384] = v;
            else g4[w - 24576] = v;
        }
        return;
    }
    // prep role: su for queries; packed [kx,ky,kz,sk] per known point
    int i = (blockIdx.x - GDOT_BLOCKS) * 256 + threadIdx.x;
    if (i < 320) return;   // wc handled by k_wc_v10 (must precede gdot readers)
    int j = i - 320;
    if (j < NQ) {
        const float* p = pts + (size_t)j * 3;
        su[j] = np_sqnorm(p[0], p[1], p[2]);
        return;
    }
    j -= NQ;
    if (j < B_ * M2) {
        const float* p = xyz2 + (size_t)j * 3;
        pk2[j] = make_float4(p[0], p[1], p[2], np_sqnorm(p[0], p[1], p[2]));
        return;
    }
    j -= B_ * M2;
    if (j < B_ * M3) {
        const float* p = xyz3 + (size_t)j * 3;
        pk3[j] = make_float4(p[0], p[1], p[2], np_sqnorm(p[0], p[1], p[2]));
        return;
    }
    j -= B_ * M3;
    if (j < B_ * M4) {
        const float* p = xyz4 + (size_t)j * 3;
        pk4[j] = make_float4(p[0], p[1], p[2], np_sqnorm(p[0], p[1], p[2]));
        return;
    }
}

__global__ void k_wc_v10(const float* __restrict__ w_fc, const float* __restrict__ w_cls,
                         float* __restrict__ wc) {
    int c = blockIdx.x * 256 + threadIdx.x;
    if (c < 320) {
        float acc = 0.f;
#pragma unroll
        for (int j = 0; j < 64; ++j) acc = fmaf(w_fc[c * 64 + j], w_cls[j], acc);
        wc[c] = acc;
    }
}

// ---------------------------------------------------------------- kernel 2
// Pass A: values-only top-3 over a QUARTER subset (first 256 of alternating
// 512-segments). LDS-staged candidate stream: coalesced vector loads ->
// uniform ds_read_b128 broadcast (replaces the slow scalar s_load stream).
#define STEP_A(KV)                                                          \
    {                                                                       \
        float d_ = ref_dist(suq, ux, uy, uz, KV.x, KV.y, KV.z, KV.w);       \
        float m1_ = __builtin_amdgcn_fmed3f(d_, a0, a1);                    \
        float m2_ = __builtin_amdgcn_fmed3f(d_, a1, a2);                    \
        a0 = fminf(d_, a0); a1 = m1_; a2 = m2_;                             \
    }

__launch_bounds__(256)
__global__ void k_scanA_v10(const float* __restrict__ pts,
                            const float4* __restrict__ pk2, const float4* __restrict__ pk3,
                            const float4* __restrict__ pk4,
                            const float* __restrict__ su,
                            float* __restrict__ ndA) {
    __shared__ float4 stg[4][256];               // 16 KB/block
    int tid  = blockIdx.x * 256 + threadIdx.x;
    int job  = __builtin_amdgcn_readfirstlane(tid >> 6);
    int w    = threadIdx.x >> 6;
    int lane = threadIdx.x & 63;

    int qtile = job / NLA;          // scalar
    int a     = job - qtile * NLA;  // 0..13
    int b     = qtile >> 7;
    int q     = (qtile << 6) + lane;

    float ux = pts[q * 3 + 0], uy = pts[q * 3 + 1], uz = pts[q * 3 + 2];
    float suq = su[q];

    const float4* kp;
    if (a < 8)       kp = pk2 + (size_t)b * M2 + (a << 10);        // lvl2: 8x256 of 8192
    else if (a < 12) kp = pk3 + (size_t)b * M3 + ((a - 8) << 10);  // lvl3: 4x256 of 4096
    else             kp = pk4 + (size_t)b * M4 + ((a - 12) << 10); // lvl4: 2x256 of 2048

#pragma unroll
    for (int j = 0; j < 4; ++j) stg[w][lane + j * 64] = kp[lane + j * 64];
    __syncthreads();

    float a0 = 3e38f, a1 = 3e38f, a2 = 3e38f;
    for (int t0 = 0; t0 < 256; t0 += 8) {
        float4 kv0 = stg[w][t0 + 0], kv1 = stg[w][t0 + 1], kv2 = stg[w][t0 + 2], kv3 = stg[w][t0 + 3];
        float4 kv4 = stg[w][t0 + 4], kv5 = stg[w][t0 + 5], kv6 = stg[w][t0 + 6], kv7 = stg[w][t0 + 7];
        STEP_A(kv0); STEP_A(kv1); STEP_A(kv2); STEP_A(kv3);
        STEP_A(kv4); STEP_A(kv5); STEP_A(kv6); STEP_A(kv7);
    }
    int base = job * 192 + lane;
    ndA[base]       = a0;
    ndA[base + 64]  = a1;
    ndA[base + 128] = a2;
}

// ---------------------------------------------------------------- kernel 3
// Pass B: full scan, slots init to Tp = nextafter(T); gate fires only for
// d <= T (~14%). LDS-staged candidate stream (same semantics as R7).
#define SCAN_STEP(KV, J)                                                    \
    {                                                                       \
        float d = ref_dist(suq, ux, uy, uz, KV.x, KV.y, KV.z, KV.w);        \
        bool c2 = d < d2;                                                   \
        if (__any(c2)) {                                                    \
            int   ti = mbase + t0 + (J);                                    \
            bool  c0 = d < d0, c1 = d < d1;                                 \
            int   n0  = c0 ? ti : i0;                                       \
            int   in0 = c0 ? i0 : ti;                                       \
            int   n1  = c1 ? in0 : i1;                                      \
            int   in1 = c1 ? i1 : ti;                                       \
            int   n2  = c2 ? in1 : i2;                                      \
            float m0 = fminf(d, d0);                                        \
            float m1 = __builtin_amdgcn_fmed3f(d, d0, d1);                  \
            float m2 = __builtin_amdgcn_fmed3f(d, d1, d2);                  \
            d0 = m0; d1 = m1; d2 = m2; i0 = n0; i1 = n1; i2 = n2;           \
        }                                                                   \
    }

__launch_bounds__(256)
__global__ void k_scanB_v10(const float* __restrict__ pts,
                            const float4* __restrict__ pk2, const float4* __restrict__ pk3,
                            const float4* __restrict__ pk4,
                            const float* __restrict__ su,
                            const float* __restrict__ ndA,
                            float* __restrict__ nd, int* __restrict__ ni) {
    __shared__ float4 stg[4][SEG];               // 32 KB/block -> 5 blocks/CU
    int tid  = blockIdx.x * 256 + threadIdx.x;
    int job  = __builtin_amdgcn_readfirstlane(tid >> 6);
    int w    = threadIdx.x >> 6;
    int lane = threadIdx.x & 63;

    int qtile = job / NLS;          // scalar
    int ls    = job - qtile * NLS;  // 0..27
    int b     = qtile >> 7;
    int q     = (qtile << 6) + lane;

    float ux = pts[q * 3 + 0], uy = pts[q * 3 + 1], uz = pts[q * 3 + 2];
    float suq = su[q];

    const float4* kp; int mbase, a0, na;
    if (ls < 16)      { mbase = ls << 9;         kp = pk2 + (size_t)b * M2 + mbase; a0 = 0;  na = 8; }
    else if (ls < 24) { mbase = (ls - 16) << 9;  kp = pk3 + (size_t)b * M3 + mbase; a0 = 8;  na = 4; }
    else              { mbase = (ls - 24) << 9;  kp = pk4 + (size_t)b * M4 + mbase; a0 = 12; na = 2; }

    // stage this wave's 512-candidate segment into LDS (coalesced)
#pragma unroll
    for (int j = 0; j < 8; ++j) stg[w][lane + j * 64] = kp[lane + j * 64];

    // T = 3rd-min of this level's pass-A triples (certified >= d3) while loads land
    float t0v = 3e38f, t1v = 3e38f, t2v = 3e38f;
    for (int a = a0; a < a0 + na; ++a) {
        int jb = (qtile * NLA + a) * 192 + lane;
#pragma unroll
        for (int k = 0; k < 3; ++k) {
            float v = ndA[jb + k * 64];
            float m1 = __builtin_amdgcn_fmed3f(v, t0v, t1v);
            float m2 = __builtin_amdgcn_fmed3f(v, t1v, t2v);
            t0v = fminf(v, t0v); t1v = m1; t2v = m2;
        }
    }
    __syncthreads();

    // Tp = next representable float above T (d == T must remain insertable)
    float T = t2v;
    int tb = __float_as_int(T);
    if (T == 0.0f) tb = 1;
    else tb = (T > 0.0f) ? tb + 1 : tb - 1;
    float Tp = __int_as_float(tb);

    float d0 = Tp, d1 = Tp, d2 = Tp;
    int   i0 = mbase, i1 = mbase, i2 = mbase;

    for (int t0 = 0; t0 < SEG; t0 += 8) {
        float4 kv0 = stg[w][t0 + 0], kv1 = stg[w][t0 + 1], kv2 = stg[w][t0 + 2], kv3 = stg[w][t0 + 3];
        float4 kv4 = stg[w][t0 + 4], kv5 = stg[w][t0 + 5], kv6 = stg[w][t0 + 6], kv7 = stg[w][t0 + 7];
        SCAN_STEP(kv0, 0); SCAN_STEP(kv1, 1); SCAN_STEP(kv2, 2); SCAN_STEP(kv3, 3);
        SCAN_STEP(kv4, 4); SCAN_STEP(kv5, 5); SCAN_STEP(kv6, 6); SCAN_STEP(kv7, 7);
    }
    int base = job * 192 + lane;         // [job][k][lane] -> coalesced
    nd[base]       = d0;  ni[base]       = i0;
    nd[base + 64]  = d1;  ni[base + 64]  = i1;
    nd[base + 128] = d2;  ni[base + 128] = i2;
}

// ---------------------------------------------------------------- kernel 4
// Merge: one thread per (query, level). Segments ascending -> stable ties.
// Tp-padded slots lose every strict-< comparison to the >=3 real candidates.
template <int NSEG>
__device__ __forceinline__ double merge_level(int qtile, int lane, int ls0,
                                              const float* __restrict__ nd,
                                              const int* __restrict__ ni,
                                              const float* __restrict__ g) {
    float d0 = 3e38f, d1 = 3e38f, d2 = 3e38f;
    int   i0 = 0, i1 = 0, i2 = 0;
#pragma unroll
    for (int s = 0; s < NSEG; ++s) {
        int jb = ((qtile * NLS) + ls0 + s) * 192 + lane;
#pragma unroll
        for (int k = 0; k < 3; ++k) {
            float d  = nd[jb + k * 64];
            int  idx = ni[jb + k * 64];
            if (d < d2) {
                if (d < d1) {
                    d2 = d1; i2 = i1;
                    if (d < d0) { d1 = d0; i1 = i0; d0 = d; i0 = idx; }
                    else        { d1 = d;  i1 = idx; }
                } else { d2 = d; i2 = idx; }
            }
        }
    }
    // referee weights, bit-exact fp32: r=1/(d+1e-8); w=r/((r0+r1)+r2)
    float r0 = __fdiv_rn(1.0f, __fadd_rn(d0, 1e-8f));
    float r1 = __fdiv_rn(1.0f, __fadd_rn(d1, 1e-8f));
    float r2 = __fdiv_rn(1.0f, __fadd_rn(d2, 1e-8f));
    float s  = __fadd_rn(__fadd_rn(r0, r1), r2);
    float w0 = __fdiv_rn(r0, s), w1 = __fdiv_rn(r1, s), w2 = __fdiv_rn(r2, s);
    return (double)w0 * (double)g[i0] + (double)w1 * (double)g[i1]
         + (double)w2 * (double)g[i2];
}

__global__ void k_merge_v10(const float* __restrict__ nd, const int* __restrict__ ni,
                            const float* __restrict__ g2, const float* __restrict__ g3,
                            const float* __restrict__ g4,
                            double* __restrict__ part) {
    int lvl = blockIdx.x >> 6;                       // 64 blocks per level
    int q   = ((blockIdx.x & 63) << 8) + threadIdx.x;
    int qtile = q >> 6, lane = q & 63;
    int b = q >> 13;

    double v;
    if (lvl == 0)      v = merge_level<16>(qtile, lane, 0,  nd, ni, g2 + b * M2);
    else if (lvl == 1) v = merge_level<8>(qtile, lane, 16, nd, ni, g3 + b * M3);
    else               v = merge_level<4>(qtile, lane, 24, nd, ni, g4 + b * M4);
    part[lvl * NQ + q] = v;
}

// ---------------------------------------------------------------- kernel 5
__global__ void k_sum_v10(const double* __restrict__ part, float* __restrict__ out) {
    int q = blockIdx.x * 256 + threadIdx.x;
    out[q] = (float)(part[q] + part[NQ + q] + part[2 * NQ + q]);
}

// ---------------------------------------------------------------- launch
extern "C" void kernel_launch(void* const* d_in, const int* in_sizes, int n_in,
                              void* d_out, int out_size, void* d_ws, size_t ws_size,
                              hipStream_t stream) {
    const float* pts   = (const float*)d_in[0];
    const float* xyz2  = (const float*)d_in[1];
    const float* feat2 = (const float*)d_in[2];
    const float* xyz3  = (const float*)d_in[3];
    const float* feat3 = (const float*)d_in[4];
    const float* xyz4  = (const float*)d_in[5];
    const float* feat4 = (const float*)d_in[6];
    const float* w_fc  = (const float*)d_in[7];
    const float* w_cls = (const float*)d_in[8];
    float* out = (float*)d_out;

    // workspace layout, ~14.4 MB
    float*  wc  = (float*)d_ws;             // 320
    float*  g2  = wc + 320;                 // 16384
    float*  g3  = g2 + 16384;               // 8192
    float*  g4  = g3 + 8192;                // 4096
    float*  su  = g4 + 4096;                // 16384  (float ofs 28992)
    float4* pk2 = (float4*)(su + 16384);    // 16384 float4 (float ofs 45376, 16B aligned)
    float4* pk3 = pk2 + B_ * M2;            // 8192 float4
    float4* pk4 = pk3 + B_ * M3;            // 4096 float4
    float*  ndA = (float*)(pk4 + B_ * M4);  // NJOBSA*192 = 688128 floats
    float*  nd  = ndA + NJOBSA * 192;       // NJOBS*192 = 1376256 floats
    int*    ni  = (int*)(nd + NJOBS * 192); // 1376256 ints
    // part[3*NQ] doubles alias su..pk3 (dead after scanB): 393216 B
    double* part = (double*)((char*)d_ws + (size_t)28992 * 4);

    k_wc_v10<<<2, 256, 0, stream>>>(w_fc, w_cls, wc);
    k_front_v10<<<FRONT_BLOCKS, 256, 0, stream>>>(
        w_fc, w_cls, pts, xyz2, xyz3, xyz4, feat2, feat3, feat4,
        wc, su, pk2, pk3, pk4, g2, g3, g4);
    k_scanA_v10<<<NJOBSA / 4, 256, 0, stream>>>(pts, pk2, pk3, pk4, su, ndA);
    k_scanB_v10<<<NJOBS / 4, 256, 0, stream>>>(pts, pk2, pk3, pk4, su, ndA, nd, ni);
    k_merge_v10<<<192, 256, 0, stream>>>(nd, ni, g2, g3, g4, part);
    k_sum_v10<<<64, 256, 0, stream>>>(part, out);
}

// Round 11
// 87.046 us; speedup vs baseline: 1.6788x; 1.4784x over previous
//
#include <hip/hip_runtime.h>

// Problem constants (from setup_inputs)
#define B_     2
#define NQ     16384     // B*N
#define M2     8192
#define M3     4096
#define M4     2048
#define NBIN   64
#define GDOT_BLOCKS 7168
#define SCAT_K_BLOCKS 112   // 32+32+16+16+8+8
#define SCAT_Q_BLOCKS 64    // 32+32
#define K2_BLOCKS (GDOT_BLOCKS + SCAT_K_BLOCKS + SCAT_Q_BLOCKS)

// Referee model (jax/XLA, verified R4): d = (su - 2*p) + sk, left-to-right fp32.
// su/sk: elementwise square + sequential reduce, NO FMA.
// p: K=3 GEMM ascending-k FMA chain. fl(2p) exact -> fmaf(-2,p,su) form ok.
__device__ __forceinline__ float np_sqnorm(float x, float y, float z) {
    return __fadd_rn(__fadd_rn(__fmul_rn(x, x), __fmul_rn(y, y)), __fmul_rn(z, z));
}
__device__ __forceinline__ float ref_dist(float su, float ux, float uy, float uz,
                                          float kx, float ky, float kz, float sk) {
    float p = fmaf(uz, kz, fmaf(uy, ky, __fmul_rn(ux, kx)));
    return __fadd_rn(fmaf(-2.0f, p, su), sk);
}
__device__ __forceinline__ int zbin(float z) {
    int b = (int)(z * 64.0f);
    return min(63, max(0, b));
}
// sortable fp32 <-> uint32 (monotone bijection, handles negatives)
__device__ __forceinline__ unsigned skey32(float d) {
    int b = __float_as_int(d);
    return (unsigned)(b ^ ((b >> 31) | 0x80000000));
}
__device__ __forceinline__ float unskey32(unsigned u) {
    int m = ((int)u < 0) ? 0x80000000 : (int)0xFFFFFFFF;
    return __int_as_float((int)(u ^ (unsigned)m));
}

// ---------------------------------------------------------------- kernel 1
// wc fold (blocks 0-1) + per-group z-hist + prefix (blocks 2-9).
// Groups: 0,1=lvl2 b0,b1  2,3=lvl3  4,5=lvl4  6,7=queries b0,b1.
__global__ void k_setup_v11(const float* __restrict__ w_fc, const float* __restrict__ w_cls,
                            const float* __restrict__ pts,
                            const float* __restrict__ xyz2, const float* __restrict__ xyz3,
                            const float* __restrict__ xyz4,
                            float* __restrict__ wc, int* __restrict__ bs,
                            int* __restrict__ cur) {
    int bx = blockIdx.x, tid = threadIdx.x;
    if (bx < 2) {
        int c = bx * 256 + tid;
        if (c < 320) {
            float acc = 0.f;
#pragma unroll
            for (int j = 0; j < 64; ++j) acc = fmaf(w_fc[c * 64 + j], w_cls[j], acc);
            wc[c] = acc;
        }
        return;
    }
    int g = bx - 2;
    const float* src; int M;
    if (g < 2)      { src = xyz2 + g * M2 * 3;       M = M2; }
    else if (g < 4) { src = xyz3 + (g - 2) * M3 * 3; M = M3; }
    else if (g < 6) { src = xyz4 + (g - 4) * M4 * 3; M = M4; }
    else            { src = pts  + (g - 6) * 8192 * 3; M = 8192; }
    __shared__ int h[NBIN];
    if (tid < NBIN) h[tid] = 0;
    __syncthreads();
    for (int j = tid; j < M; j += 256) atomicAdd(&h[zbin(src[j * 3 + 2])], 1);
    __syncthreads();
    if (tid == 0) {
        int run = 0;
        for (int b = 0; b < NBIN; ++b) { bs[g * 65 + b] = run; run += h[b]; }
        bs[g * 65 + 64] = run;
    }
    __syncthreads();
    if (tid < NBIN) cur[g * 64 + tid] = bs[g * 65 + tid];
}

// ---------------------------------------------------------------- kernel 2
// gdot (one wave per known point) + z-binned scatter of known pts & queries.
__global__ void k_build_v11(const float* __restrict__ pts,
                            const float* __restrict__ xyz2, const float* __restrict__ xyz3,
                            const float* __restrict__ xyz4,
                            const float* __restrict__ f2, const float* __restrict__ f3,
                            const float* __restrict__ f4, const float* __restrict__ wc,
                            float* __restrict__ g2, float* __restrict__ g3,
                            float* __restrict__ g4,
                            float4* __restrict__ pk, int* __restrict__ oi,
                            float4* __restrict__ uq, int* __restrict__ qmap,
                            int* __restrict__ cur) {
    int bx = blockIdx.x, tid = threadIdx.x;
    if (bx < GDOT_BLOCKS) {
        int gid  = bx * 256 + tid;
        int w    = gid >> 6;
        int lane = gid & 63;
        float v;
        if (w < 16384) {
            v = f2[(size_t)w * 64 + lane] * wc[lane];
        } else if (w < 24576) {
            size_t base = (size_t)(w - 16384) * 128;
            v = fmaf(f3[base + 64 + lane], wc[128 + lane], f3[base + lane] * wc[64 + lane]);
        } else {
            size_t base = (size_t)(w - 24576) * 128;
            v = fmaf(f4[base + 64 + lane], wc[256 + lane], f4[base + lane] * wc[192 + lane]);
        }
        for (int off = 32; off; off >>= 1) v += __shfl_down(v, off, 64);
        if (lane == 0) {
            if (w < 16384) g2[w] = v;
            else if (w < 24576) g3[w - 16384] = v;
            else g4[w - 24576] = v;
        }
        return;
    }
    bx -= GDOT_BLOCKS;
    __shared__ int cnt[NBIN], base[NBIN];
    if (tid < NBIN) cnt[tid] = 0;
    __syncthreads();
    if (bx < SCAT_K_BLOCKS) {
        int g, j0;
        if (bx < 32)       { g = 0; j0 = bx * 256; }
        else if (bx < 64)  { g = 1; j0 = (bx - 32) * 256; }
        else if (bx < 80)  { g = 2; j0 = (bx - 64) * 256; }
        else if (bx < 96)  { g = 3; j0 = (bx - 80) * 256; }
        else if (bx < 104) { g = 4; j0 = (bx - 96) * 256; }
        else               { g = 5; j0 = (bx - 104) * 256; }
        const float* src = (g < 2) ? xyz2 + g * M2 * 3
                         : (g < 4) ? xyz3 + (g - 2) * M3 * 3
                                   : xyz4 + (g - 4) * M4 * 3;
        int gb = (g < 2) ? g * M2 : (g < 4) ? 16384 + (g - 2) * M3 : 24576 + (g - 4) * M4;
        int j = j0 + tid;
        float x = src[j * 3], y = src[j * 3 + 1], z = src[j * 3 + 2];
        int bin = zbin(z);
        int off = atomicAdd(&cnt[bin], 1);
        __syncthreads();
        if (tid < NBIN) base[tid] = atomicAdd(&cur[g * 64 + tid], cnt[tid]);
        __syncthreads();
        int slot = gb + base[bin] + off;
        pk[slot] = make_float4(x, y, z, np_sqnorm(x, y, z));
        oi[slot] = j;                          // orig index within (level,batch)
        return;
    }
    bx -= SCAT_K_BLOCKS;
    {   // query scatter
        int b = bx >> 5;
        int j = (bx & 31) * 256 + tid;         // [0,8192) within batch
        const float* src = pts + (size_t)b * 8192 * 3;
        float x = src[j * 3], y = src[j * 3 + 1], z = src[j * 3 + 2];
        int bin = zbin(z);
        int g = 6 + b;
        int off = atomicAdd(&cnt[bin], 1);
        __syncthreads();
        if (tid < NBIN) base[tid] = atomicAdd(&cur[g * 64 + tid], cnt[tid]);
        __syncthreads();
        int slot = b * 8192 + base[bin] + off;
        uq[slot]   = make_float4(x, y, z, np_sqnorm(x, y, z));
        qmap[slot] = b * 8192 + j;             // orig global query index
    }
}

// ---------------------------------------------------------------- kernel 3
// Wave = one sorted query; lanes stride candidates (per-lane coalesced float4).
// Per level: T-phase (per-lane values top-3 over own bin -> shfl_xor butterfly
// -> exact bin 3rd-min T), then windowed scan with wave-uniform lex top-3 of
// u64 keys (skey(d)<<32 | orig_idx), gated by key<K2 + ballot/readlane insert.
// Deterministic under nondeterministic bin scatter; matches stable top-k ties.
__launch_bounds__(256)
__global__ void k_scan_v11(const float4* __restrict__ pk, const int* __restrict__ oi,
                           const float4* __restrict__ uq, const int* __restrict__ qmap,
                           const int* __restrict__ bs,
                           const float* __restrict__ g2, const float* __restrict__ g3,
                           const float* __restrict__ g4,
                           float* __restrict__ out) {
    int sq   = blockIdx.x * 4 + (threadIdx.x >> 6);   // sorted query id
    int lane = threadIdx.x & 63;
    int b    = sq >> 13;

    float4 u = uq[sq];
    float ux = u.x, uy = u.y, uz = u.z, suq = u.w;

    double acc = 0.0;

#pragma unroll 1
    for (int lvl = 0; lvl < 3; ++lvl) {
        int gb; const float* gl;
        if (lvl == 0)      { gb = b * M2;         gl = g2 + b * M2; }
        else if (lvl == 1) { gb = 16384 + b * M3; gl = g3 + b * M3; }
        else               { gb = 24576 + b * M4; gl = g4 + b * M4; }
        const float4* pkg = pk + gb;
        const int*    oig = oi + gb;
        const int*    bsg = bs + (lvl * 2 + b) * 65;

        // ---- T phase: own-bin values-only top-3, butterfly to exact bin 3rd-min
        int bq = zbin(uz);
        int S0 = bsg[bq], E0 = bsg[bq + 1];
        float a0 = 3e38f, a1 = 3e38f, a2 = 3e38f;
        for (int t = S0 + lane; t < E0; t += 64) {
            float4 kv = pkg[t];
            float d = ref_dist(suq, ux, uy, uz, kv.x, kv.y, kv.z, kv.w);
            float m1 = __builtin_amdgcn_fmed3f(d, a0, a1);
            float m2 = __builtin_amdgcn_fmed3f(d, a1, a2);
            a0 = fminf(d, a0); a1 = m1; a2 = m2;
        }
#pragma unroll
        for (int off = 1; off < 64; off <<= 1) {
            float b0 = __shfl_xor(a0, off, 64);
            float b1 = __shfl_xor(a1, off, 64);
            float b2 = __shfl_xor(a2, off, 64);
            float m1 = __builtin_amdgcn_fmed3f(b0, a0, a1);
            float m2 = __builtin_amdgcn_fmed3f(b0, a1, a2);
            a0 = fminf(b0, a0); a1 = m1; a2 = m2;
            m1 = __builtin_amdgcn_fmed3f(b1, a0, a1);
            m2 = __builtin_amdgcn_fmed3f(b1, a1, a2);
            a0 = fminf(b1, a0); a1 = m1; a2 = m2;
            m1 = __builtin_amdgcn_fmed3f(b2, a0, a1);
            m2 = __builtin_amdgcn_fmed3f(b2, a1, a2);
            a0 = fminf(b2, a0); a1 = m1; a2 = m2;
        }
        float T = a2;   // lane-uniform; 3e38 if own bin < 3 pts -> full window

        // ---- window = bins covering z +- sqrt(T + 1e-5)  (exact, margin >> fp err)
        float s  = sqrtf(__fadd_rn(T, 1e-5f));
        float zl = fmaxf(uz - s, 0.0f);
        float zh = fminf(uz + s, 0.999999f);
        int BL = min(63, (int)(zl * 64.0f));
        int BH = min(63, (int)(zh * 64.0f));
        int S = bsg[BL], E = bsg[BH + 1];

        int tbits = __float_as_int(T);
        float Tp = (T > 0.0f) ? __int_as_float(tbits + 1)
                 : (T < 0.0f) ? __int_as_float(tbits - 1) : 1e-45f;
        unsigned long long PAD = ((unsigned long long)skey32(Tp) << 32) | 0xFFFFFFFFull;
        unsigned long long K0 = PAD, K1 = PAD, K2 = PAD;

        int rounds = (E - S + 63) >> 6;       // uniform trip count (keeps K uniform)
        int t = S + lane;
        for (int r = 0; r < rounds; ++r, t += 64) {
            unsigned long long kk = ~0ull;    // never inserts
            if (t < E) {
                float4 kv = pkg[t];
                int    o  = oig[t];
                float d = ref_dist(suq, ux, uy, uz, kv.x, kv.y, kv.z, kv.w);
                kk = ((unsigned long long)skey32(d) << 32) | (unsigned)o;
            }
            unsigned long long m = __ballot(kk < K2);
            while (m) {                       // scalar loop, ~6-10 fires per q-lvl
                int l = __ffsll((long long)m) - 1;
                m &= m - 1;
                int hi = __builtin_amdgcn_readlane((int)(kk >> 32), l);
                int lo = __builtin_amdgcn_readlane((int)(kk & 0xFFFFFFFFull), l);
                unsigned long long kl = ((unsigned long long)(unsigned)hi << 32)
                                      | (unsigned)lo;
                if (kl < K2) {
                    bool c1 = kl < K1, c0 = kl < K0;
                    K2 = c1 ? K1 : kl;
                    K1 = c0 ? K0 : (c1 ? kl : K1);
                    K0 = c0 ? kl : K0;
                }
            }
        }

        // ---- referee weights (bit-exact fp32) + f64 g-fold
        float d0 = unskey32((unsigned)(K0 >> 32));
        float d1 = unskey32((unsigned)(K1 >> 32));
        float d2 = unskey32((unsigned)(K2 >> 32));
        int i0 = (int)(K0 & 0xFFFFFFFFull);
        int i1 = (int)(K1 & 0xFFFFFFFFull);
        int i2 = (int)(K2 & 0xFFFFFFFFull);
        float r0 = __fdiv_rn(1.0f, __fadd_rn(d0, 1e-8f));
        float r1 = __fdiv_rn(1.0f, __fadd_rn(d1, 1e-8f));
        float r2 = __fdiv_rn(1.0f, __fadd_rn(d2, 1e-8f));
        float sw = __fadd_rn(__fadd_rn(r0, r1), r2);
        float w0 = __fdiv_rn(r0, sw), w1 = __fdiv_rn(r1, sw), w2 = __fdiv_rn(r2, sw);
        acc += (double)w0 * (double)gl[i0] + (double)w1 * (double)gl[i1]
             + (double)w2 * (double)gl[i2];
    }
    if (lane == 0) out[qmap[sq]] = (float)acc;
}

// ---------------------------------------------------------------- launch
extern "C" void kernel_launch(void* const* d_in, const int* in_sizes, int n_in,
                              void* d_out, int out_size, void* d_ws, size_t ws_size,
                              hipStream_t stream) {
    const float* pts   = (const float*)d_in[0];
    const float* xyz2  = (const float*)d_in[1];
    const float* feat2 = (const float*)d_in[2];
    const float* xyz3  = (const float*)d_in[3];
    const float* feat3 = (const float*)d_in[4];
    const float* xyz4  = (const float*)d_in[5];
    const float* feat4 = (const float*)d_in[6];
    const float* w_fc  = (const float*)d_in[7];
    const float* w_cls = (const float*)d_in[8];
    float* out = (float*)d_out;

    // workspace layout (~1.02 MB)
    float4* pk   = (float4*)d_ws;          // 28672 float4
    float4* uq   = pk + 28672;             // 16384 float4
    float*  g2   = (float*)(uq + 16384);   // 16384
    float*  g3   = g2 + 16384;             // 8192
    float*  g4   = g3 + 8192;              // 4096
    float*  wc   = g4 + 4096;              // 320
    int*    oi   = (int*)(wc + 320);       // 28672
    int*    qmap = oi + 28672;             // 16384
    int*    bs   = qmap + 16384;           // 8*65
    int*    cur  = bs + 520;               // 8*64

    k_setup_v11<<<10, 256, 0, stream>>>(w_fc, w_cls, pts, xyz2, xyz3, xyz4, wc, bs, cur);
    k_build_v11<<<K2_BLOCKS, 256, 0, stream>>>(pts, xyz2, xyz3, xyz4,
                                               feat2, feat3, feat4, wc,
                                               g2, g3, g4, pk, oi, uq, qmap, cur);
    k_scan_v11<<<4096, 256, 0, stream>>>(pk, oi, uq, qmap, bs, g2, g3, g4, out);
}